// Round 5
// baseline (145.927 us; speedup 1.0000x reference)
//
#include <hip/hip_runtime.h>
#include <math.h>

// Problem constants
#define BB 16
#define TT 2048
#define CC 512
#define GG 2
#define DD 256      // C/G
#define VV 320
#define DT (DD*TT)
#define NOUT ((size_t)BB*TT*CC)

// Workspace layout (bytes) — total 68,359,680 (~65.2 MiB)
#define OFF_H      0ULL
#define SZ_H       ((size_t)BB*GG*TT*DD*4)          // 67108864
#define OFF_PART   (OFF_H + SZ_H)                    // 512 blocks * 2 doubles
#define OFF_MUSIG  (OFF_PART + 4096ULL*2*8)
#define OFF_ESQ    (OFF_MUSIG + 32ULL*2*4)
#define OFF_CNT    (OFF_ESQ + (size_t)GG*VV*4)
#define OFF_LOSS   (OFF_CNT + (size_t)GG*VV*4)
#define OFF_EMBH   67180032ULL                       // G*8*4*320*8 halfs = 327680 B
#define OFF_EMBL   (OFF_EMBH + 327680ULL)
#define OFF_WH     67835392ULL                       // G*8*4*256*8 halfs = 262144 B
#define OFF_WL     (OFF_WH + 262144ULL)

typedef _Float16 half8   __attribute__((ext_vector_type(8)));
typedef _Float16 half4_t __attribute__((ext_vector_type(4)));
typedef float    f32x4   __attribute__((ext_vector_type(4)));

#define MARGIN 5e-4f

// blocks 0..39: esq + emb fp16 hi/lo planes. block 40: init. blocks 41..56: W planes.
// emb plane[g][c][hgrp][v][j], k = c*32 + hgrp*4 + (j&3) + 16*(j>>2)
// W   plane[g][c][hgrp][o][j], same k-map.
__global__ __launch_bounds__(256) void k_emb(const float* __restrict__ emb,
                                             const float* __restrict__ w,
                                             _Float16* __restrict__ embHp,
                                             _Float16* __restrict__ embLp,
                                             _Float16* __restrict__ wHp,
                                             _Float16* __restrict__ wLp,
                                             float* __restrict__ esq,
                                             unsigned* __restrict__ counts,
                                             float* __restrict__ loss) {
  int blk = blockIdx.x;
  int tid = threadIdx.x;
  if (blk == 40) {      // init block
    for (int i = tid; i < GG*VV; i += 256) counts[i] = 0u;
    if (tid == 0) *loss = 0.0f;
    return;
  }
  if (blk >= 41) {      // W-split blocks
    int wblk = blk - 41;
    int g = wblk >> 3, c = wblk & 7;
    int o = tid;
    const float* wrow = w + (size_t)(g*DD + o)*DD + (c << 5);
    #pragma unroll
    for (int hgrp = 0; hgrp < 4; ++hgrp) {
      float4 f1 = *(const float4*)(wrow + (hgrp << 2));
      float4 f2 = *(const float4*)(wrow + (hgrp << 2) + 16);
      float fv[8] = {f1.x, f1.y, f1.z, f1.w, f2.x, f2.y, f2.z, f2.w};
      half8 vh, vl;
      #pragma unroll
      for (int e = 0; e < 8; ++e) {
        _Float16 hh = (_Float16)fv[e];
        vh[e] = hh;
        vl[e] = (_Float16)(fv[e] - (float)hh);
      }
      size_t base = (((((size_t)(g*8 + c)) << 2) + hgrp) << 8) + o;   // units of 8 halfs
      *(half8*)(wHp + (base << 3)) = vh;
      *(half8*)(wLp + (base << 3)) = vl;
    }
    return;
  }
  int g = blk / 20;
  int v0 = (blk % 20) * 16;
  int vl = tid >> 4, dl = tid & 15;
  int v = v0 + vl;
  double sq = 0.0;
  #pragma unroll
  for (int k = 0; k < 16; k++) {
    int d = dl + (k << 4);
    float e = emb[((size_t)v*GG + g)*DD + d];
    sq += (double)e * (double)e;
  }
  #pragma unroll
  for (int m = 1; m < 16; m <<= 1) sq += __shfl_xor(sq, m);
  if (dl == 0) esq[g*VV + v] = (float)sq;

  const int hgrp = dl >> 2, jb = dl & 3;
  #pragma unroll
  for (int c = 0; c < 8; ++c) {
    int k0 = (c << 5) + (hgrp << 2) + jb;
    int k1 = k0 + 16;
    float e0 = emb[((size_t)v*GG + g)*DD + k0];
    float e1 = emb[((size_t)v*GG + g)*DD + k1];
    size_t base = (((size_t)(g*8 + c)*4 + hgrp)*320 + v)*8;
    _Float16 h0 = (_Float16)e0, h1 = (_Float16)e1;
    embHp[base + jb]     = h0;
    embHp[base + jb + 4] = h1;
    embLp[base + jb]     = (_Float16)(e0 - (float)h0);
    embLp[base + jb + 4] = (_Float16)(e1 - (float)h1);
  }
}

// Conv GEMM, barrier-free K-loop: A (x) from registers with 1-chunk prefetch,
// B (W fp16 planes) direct from global (L2-resident). Bit-identical math to R4.
__global__ __launch_bounds__(256, 2) void k_conv2(const float* __restrict__ x,
                                                  const _Float16* __restrict__ wH,
                                                  const _Float16* __restrict__ wL,
                                                  float* __restrict__ h,
                                                  double* __restrict__ part) {
  __shared__ double r1[4], r2[4];
  const int bid = blockIdx.x;         // 512
  const int bg = bid >> 4, tt = bid & 15;
  const int b = bg >> 1, g = bg & 1;
  const int tid = threadIdx.x;
  const int wv = tid >> 6, lane = tid & 63;
  const int l15 = tid & 15, lh = lane >> 4;
  const int t0w = (tt << 7) + (wv << 5);

  f32x4 acc[2][16];
  #pragma unroll
  for (int tf = 0; tf < 2; ++tf)
    #pragma unroll
    for (int vf = 0; vf < 16; ++vf) acc[tf][vf] = 0.0f;

  const _Float16* WHg = wH + ((size_t)g << 16);
  const _Float16* WLg = wL + ((size_t)g << 16);
  const float* xb0 = x + ((size_t)(b*TT + t0w + l15)*CC + g*DD + (lh << 2));
  const float* xb1 = xb0 + ((size_t)16)*CC;

  // prefetch chunk 0
  float4 p00 = *(const float4*)(xb0);
  float4 p01 = *(const float4*)(xb0 + 16);
  float4 p10 = *(const float4*)(xb1);
  float4 p11 = *(const float4*)(xb1 + 16);

  #pragma unroll 1
  for (int c = 0; c < 8; ++c) {
    float4 c00 = p00, c01 = p01, c10 = p10, c11 = p11;
    if (c < 7) {
      const int off = (c + 1) << 5;
      p00 = *(const float4*)(xb0 + off);
      p01 = *(const float4*)(xb0 + off + 16);
      p10 = *(const float4*)(xb1 + off);
      p11 = *(const float4*)(xb1 + off + 16);
    }
    half8 ah[2], al[2];
    {
      float fv0[8] = {c00.x, c00.y, c00.z, c00.w, c01.x, c01.y, c01.z, c01.w};
      float fv1[8] = {c10.x, c10.y, c10.z, c10.w, c11.x, c11.y, c11.z, c11.w};
      #pragma unroll
      for (int e = 0; e < 8; ++e) {
        _Float16 h0 = (_Float16)fv0[e];
        ah[0][e] = h0; al[0][e] = (_Float16)(fv0[e] - (float)h0);
        _Float16 h1 = (_Float16)fv1[e];
        ah[1][e] = h1; al[1][e] = (_Float16)(fv1[e] - (float)h1);
      }
    }
    #pragma unroll
    for (int vf = 0; vf < 16; ++vf) {
      const size_t bo = (((((size_t)(c << 2)) + lh) << 8) + (vf << 4) + l15) << 3;
      half8 bh = *(const half8*)(WHg + bo);
      half8 bl = *(const half8*)(WLg + bo);
      #pragma unroll
      for (int tf = 0; tf < 2; ++tf) {
        acc[tf][vf] = __builtin_amdgcn_mfma_f32_16x16x32_f16(ah[tf], bh, acc[tf][vf], 0, 0, 0);
        acc[tf][vf] = __builtin_amdgcn_mfma_f32_16x16x32_f16(al[tf], bh, acc[tf][vf], 0, 0, 0);
        acc[tf][vf] = __builtin_amdgcn_mfma_f32_16x16x32_f16(ah[tf], bl, acc[tf][vf], 0, 0, 0);
      }
    }
  }

  // store h + double stats (order identical to R4)
  double s1 = 0.0, s2 = 0.0;
  {
    float* hb = h + (size_t)bg*TT*DD;
    #pragma unroll
    for (int tf = 0; tf < 2; ++tf) {
      #pragma unroll
      for (int reg = 0; reg < 4; ++reg) {
        const int t = t0w + (tf << 4) + (lh << 2) + reg;
        float* hrow = hb + (size_t)t*DD + l15;
        #pragma unroll
        for (int vf = 0; vf < 16; ++vf) {
          float v = acc[tf][vf][reg];
          hrow[vf << 4] = v;
          double dv = (double)v;
          s1 += dv; s2 += dv*dv;
        }
      }
    }
  }
  #pragma unroll
  for (int m = 32; m > 0; m >>= 1) { s1 += __shfl_down(s1, m); s2 += __shfl_down(s2, m); }
  if (lane == 0) { r1[wv] = s1; r2[wv] = s2; }
  __syncthreads();
  if (tid == 0) {
    part[(size_t)bid*2]     = r1[0] + r1[1] + r1[2] + r1[3];
    part[(size_t)bid*2 + 1] = r2[0] + r2[1] + r2[2] + r2[3];
  }
}

__global__ void k_stats(const double* __restrict__ part, float* __restrict__ musig) {
  int i = threadIdx.x;
  if (i < BB*GG) {
    double s1 = 0.0, s2 = 0.0;
    for (int r = 0; r < 16; r++) { s1 += part[(i*16 + r)*2]; s2 += part[(i*16 + r)*2 + 1]; }
    double mu  = s1 / (double)DT;
    double var = s2 / (double)DT - mu*mu;
    double rs  = 1.0 / sqrt(var + 1e-5);
    musig[i*2]     = (float)mu;
    musig[i*2 + 1] = (float)rs;
  }
}

// MFMA VQ, barrier-free K-loop: A (h) normalized in-reg with 1-chunk prefetch,
// B (emb fp16 planes) direct from global. Selection + exact recheck unchanged.
__global__ __launch_bounds__(256, 2) void k_vq2(const float* __restrict__ h,
                                                const float* __restrict__ musig,
                                                const float* __restrict__ gn_w,
                                                const float* __restrict__ gn_b,
                                                const _Float16* __restrict__ embH,
                                                const _Float16* __restrict__ embL,
                                                const float* __restrict__ esq,
                                                const float* __restrict__ emb,
                                                float* __restrict__ out,
                                                unsigned* __restrict__ counts,
                                                float* __restrict__ loss) {
  __shared__ __align__(16) char smem[12288];
  float*  esqs    = (float*)smem;                // 320 f
  int*    candcnt = (int*)(smem + 1280);         // 128
  int*    bestv   = (int*)(smem + 1792);         // 128
  int*    slowl   = (int*)(smem + 2304);         // 128
  int*    nslow   = (int*)(smem + 2816);
  double* zsqs    = (double*)(smem + 2824);      // 4
  float*  scratch = (float*)(smem + 2864);       // 256 f
  unsigned short* cand = (unsigned short*)(smem + 3888);  // [128][24]
  float*  candd2  = (float*)(smem + 10032);      // 24
  float*  gnws    = (float*)(smem + 10240);      // 256 f
  float*  gnbs    = (float*)(smem + 11264);      // 256 f

  const int bid = blockIdx.x;        // 512 blocks
  const int bg  = bid >> 4;
  const int t0  = (bid & 15) << 7;
  const int b = bg >> 1, g = bg & 1;
  const int tid = threadIdx.x;
  const int lane = tid & 63, wv = tid >> 6;
  const int l15 = tid & 15, lh = lane >> 4;
  const float mu = musig[bg*2], rs = musig[bg*2 + 1];
  const float* hb = h + ((size_t)bg*TT + t0)*DD;

  gnws[tid] = gn_w[g*DD + tid];
  gnbs[tid] = gn_b[g*DD + tid];

  f32x4 acc[2][20];
  #pragma unroll
  for (int tf = 0; tf < 2; ++tf)
    #pragma unroll
    for (int vf = 0; vf < 20; ++vf) acc[tf][vf] = 0.0f;

  const _Float16* gBH = embH + (size_t)(g*8)*10240;
  const _Float16* gBL = embL + (size_t)(g*8)*10240;
  const float* gwp = gn_w + g*DD;
  const float* gbp = gn_b + g*DD;

  const float* hb0 = hb + (size_t)((wv << 5) + l15)*DD + (lh << 2);
  const float* hb1 = hb0 + ((size_t)16)*DD;

  float4 p00 = *(const float4*)(hb0);
  float4 p01 = *(const float4*)(hb0 + 16);
  float4 p10 = *(const float4*)(hb1);
  float4 p11 = *(const float4*)(hb1 + 16);

  #pragma unroll 1
  for (int c = 0; c < 8; ++c) {
    float4 c00 = p00, c01 = p01, c10 = p10, c11 = p11;
    if (c < 7) {
      const int off = (c + 1) << 5;
      p00 = *(const float4*)(hb0 + off);
      p01 = *(const float4*)(hb0 + off + 16);
      p10 = *(const float4*)(hb1 + off);
      p11 = *(const float4*)(hb1 + off + 16);
    }
    const int c32 = c << 5;
    half8 ah[2], al[2];
    {
      float4 w1 = *(const float4*)(gwp + c32 + (lh << 2));
      float4 w2 = *(const float4*)(gwp + c32 + (lh << 2) + 16);
      float4 b1 = *(const float4*)(gbp + c32 + (lh << 2));
      float4 b2 = *(const float4*)(gbp + c32 + (lh << 2) + 16);
      float wv_[8] = {w1.x, w1.y, w1.z, w1.w, w2.x, w2.y, w2.z, w2.w};
      float bv_[8] = {b1.x, b1.y, b1.z, b1.w, b2.x, b2.y, b2.z, b2.w};
      float fv0[8] = {c00.x, c00.y, c00.z, c00.w, c01.x, c01.y, c01.z, c01.w};
      float fv1[8] = {c10.x, c10.y, c10.z, c10.w, c11.x, c11.y, c11.z, c11.w};
      #pragma unroll
      for (int e = 0; e < 8; ++e) {
        float z0 = __fmul_rn(__fsub_rn(fv0[e], mu), rs);
        z0 = __fadd_rn(__fmul_rn(z0, wv_[e]), bv_[e]);
        _Float16 zh0 = (_Float16)z0;
        ah[0][e] = zh0; al[0][e] = (_Float16)(z0 - (float)zh0);
        float z1 = __fmul_rn(__fsub_rn(fv1[e], mu), rs);
        z1 = __fadd_rn(__fmul_rn(z1, wv_[e]), bv_[e]);
        _Float16 zh1 = (_Float16)z1;
        ah[1][e] = zh1; al[1][e] = (_Float16)(z1 - (float)zh1);
      }
    }
    #pragma unroll
    for (int vf = 0; vf < 20; ++vf) {
      const int v = (vf << 4) + l15;
      const size_t bo = (size_t)c*10240 + (((lh*320) + v) << 3);
      half8 bh = *(const half8*)(gBH + bo);
      half8 bl = *(const half8*)(gBL + bo);
      #pragma unroll
      for (int tf = 0; tf < 2; ++tf) {
        acc[tf][vf] = __builtin_amdgcn_mfma_f32_16x16x32_f16(ah[tf], bh, acc[tf][vf], 0, 0, 0);
        acc[tf][vf] = __builtin_amdgcn_mfma_f32_16x16x32_f16(al[tf], bh, acc[tf][vf], 0, 0, 0);
        acc[tf][vf] = __builtin_amdgcn_mfma_f32_16x16x32_f16(ah[tf], bl, acc[tf][vf], 0, 0, 0);
      }
    }
  }
  __syncthreads();

  // ---- epilogue init ----
  if (tid < 160) { esqs[tid] = esq[g*VV + tid]; esqs[tid + 160] = esq[g*VV + tid + 160]; }
  if (tid < 128) { candcnt[tid] = 0; bestv[tid] = -1; }
  if (tid == 0) *nslow = 0;
  __syncthreads();

  // selection: y = esq - 2c'; candidates within MARGIN of row min
  #pragma unroll
  for (int tf = 0; tf < 2; ++tf) {
    #pragma unroll
    for (int reg = 0; reg < 4; ++reg) {
      int row = (wv << 5) + (tf << 4) + (lh << 2) + reg;
      float y[20]; float mn = 3.4e38f;
      #pragma unroll
      for (int vf = 0; vf < 20; ++vf) {
        y[vf] = fmaf(-2.0f, acc[tf][vf][reg], esqs[(vf << 4) + l15]);
        mn = fminf(mn, y[vf]);
      }
      #pragma unroll
      for (int m = 1; m < 16; m <<= 1) mn = fminf(mn, __shfl_xor(mn, m));
      float thr = mn + MARGIN;
      #pragma unroll
      for (int vf = 0; vf < 20; ++vf) {
        if (y[vf] <= thr) {
          int pos = atomicAdd(&candcnt[row], 1);
          if (pos < 24) cand[row*24 + pos] = (unsigned short)((vf << 4) + l15);
        }
      }
    }
  }
  __syncthreads();
  if (tid < 128) {
    int cnt = candcnt[tid];
    if (cnt == 1) bestv[tid] = cand[tid*24];
    else { int p = atomicAdd(nslow, 1); slowl[p] = tid; }
  }
  __syncthreads();

  // slow path: exact re-score (bit-identical arithmetic)
  const int ns = *nslow;
  for (int i = 0; i < ns; ++i) {
    const int row = slowl[i];
    float hv = hb[(size_t)row*DD + tid];
    float z = __fmul_rn(__fsub_rn(hv, mu), rs);
    z = __fadd_rn(__fmul_rn(z, gnws[tid]), gnbs[tid]);
    scratch[tid] = z;
    double q = (double)z * (double)z;
    #pragma unroll
    for (int m = 32; m > 0; m >>= 1) q += __shfl_down(q, m);
    if (lane == 0) zsqs[wv] = q;
    __syncthreads();
    const float ze2f = (float)(zsqs[0] + zsqs[1] + zsqs[2] + zsqs[3]);
    const int cnt = candcnt[row];
    if (cnt <= 24) {
      if (tid < cnt) {
        int v = cand[row*24 + tid];
        float cc = 0.0f;
        const float* ep = emb + ((size_t)v*GG + g)*DD;
        for (int d = 0; d < DD; ++d) cc = fmaf(scratch[d], ep[d], cc);
        candd2[tid] = __fadd_rn(__fsub_rn(ze2f, __fmul_rn(2.0f, cc)), esqs[v]);
      }
      __syncthreads();
      if (tid == 0) {
        float bd = 3.4e38f; int bv = 0x7fffffff;
        for (int ci = 0; ci < cnt; ++ci) {
          int v = cand[row*24 + ci]; float d2 = candd2[ci];
          if (d2 < bd || (d2 == bd && v < bv)) { bd = d2; bv = v; }
        }
        bestv[row] = bv;
      }
    } else {
      if (tid == 0) {  // overflow fallback (effectively unreachable)
        float bd = 3.4e38f; int bv = 0x7fffffff;
        for (int v = 0; v < VV; ++v) {
          float cc = 0.0f;
          const float* ep = emb + ((size_t)v*GG + g)*DD;
          for (int d = 0; d < DD; ++d) cc = fmaf(scratch[d], ep[d], cc);
          float d2 = __fadd_rn(__fsub_rn(ze2f, __fmul_rn(2.0f, cc)), esqs[v]);
          if (d2 < bd) { bd = d2; bv = v; }
        }
        bestv[row] = bv;
      }
    }
    __syncthreads();
  }

  if (tid < 128) atomicAdd(&counts[g*VV + bestv[tid]], 1u);

  // x_out = selected embedding; loss partial
  float lp = 0.0f;
  float* ob = out + (size_t)(b*TT + t0)*CC + g*DD + tid;
  const float gw = gnws[tid], gb2 = gnbs[tid];
  for (int r = 0; r < 128; ++r) {
    int v = bestv[r];
    float e = emb[((size_t)v*GG + g)*DD + tid];
    float hv = hb[(size_t)r*DD + tid];
    float z = __fmul_rn(__fsub_rn(hv, mu), rs);
    z = __fadd_rn(__fmul_rn(z, gw), gb2);
    float df = e - z;
    lp = fmaf(df, df, lp);
    ob[(size_t)r*CC] = e;
  }
  #pragma unroll
  for (int m = 32; m > 0; m >>= 1) lp += __shfl_down(lp, m);
  if (lane == 0) scratch[wv] = lp;
  __syncthreads();
  if (tid == 0) atomicAdd(loss, scratch[0] + scratch[1] + scratch[2] + scratch[3]);
}

__global__ __launch_bounds__(256) void k_final(const unsigned* __restrict__ counts,
                                               const float* __restrict__ loss,
                                               float* __restrict__ out) {
  __shared__ float sd[256];
  int tid = threadIdx.x;
  float perp = 0.0f;
  for (int g = 0; g < GG; g++) {
    float p1 = 0.0f;
    for (int v = tid; v < VV; v += 256) {
      float p = (float)counts[g*VV + v] / 32768.0f;
      p1 += p * logf(p + 1e-7f);
    }
    sd[tid] = p1;
    __syncthreads();
    for (int s = 128; s > 0; s >>= 1) {
      if (tid < s) sd[tid] += sd[tid + s];
      __syncthreads();
    }
    if (tid == 0) perp += expf(-sd[0]);
    __syncthreads();
  }
  if (tid == 0) {
    out[NOUT]     = 1.25f * (*loss) / (float)NOUT;
    out[NOUT + 1] = perp;
  }
}

extern "C" void kernel_launch(void* const* d_in, const int* in_sizes, int n_in,
                              void* d_out, int out_size, void* d_ws, size_t ws_size,
                              hipStream_t stream) {
  const float* x   = (const float*)d_in[0];
  const float* cw  = (const float*)d_in[1];
  const float* gnw = (const float*)d_in[2];
  const float* gnb = (const float*)d_in[3];
  const float* emb = (const float*)d_in[4];
  float* out = (float*)d_out;
  char* ws = (char*)d_ws;
  float*     h      = (float*)(ws + OFF_H);
  double*    part   = (double*)(ws + OFF_PART);
  float*     musig  = (float*)(ws + OFF_MUSIG);
  float*     esq    = (float*)(ws + OFF_ESQ);
  unsigned*  counts = (unsigned*)(ws + OFF_CNT);
  float*     loss   = (float*)(ws + OFF_LOSS);
  _Float16*  embH   = (_Float16*)(ws + OFF_EMBH);
  _Float16*  embL   = (_Float16*)(ws + OFF_EMBL);
  _Float16*  wH     = (_Float16*)(ws + OFF_WH);
  _Float16*  wL     = (_Float16*)(ws + OFF_WL);

  hipLaunchKernelGGL(k_emb,   dim3(57),   dim3(256), 0, stream,
                     emb, cw, embH, embL, wH, wL, esq, counts, loss);
  hipLaunchKernelGGL(k_conv2, dim3(512),  dim3(256), 0, stream, x, wH, wL, h, part);
  hipLaunchKernelGGL(k_stats, dim3(1),    dim3(32),  0, stream, part, musig);
  hipLaunchKernelGGL(k_vq2,   dim3(512),  dim3(256), 0, stream,
                     h, musig, gnw, gnb, embH, embL, esq, emb, out, counts, loss);
  hipLaunchKernelGGL(k_final, dim3(1),    dim3(256), 0, stream, counts, loss, out);
}

// Round 6
// 103.797 us; speedup vs baseline: 1.4059x; 1.4059x over previous
//
#include <hip/hip_runtime.h>
#include <math.h>

// Problem constants
#define BB 16
#define TT 2048
#define CC 512
#define GG 2
#define DD 256      // C/G
#define VV 320
#define DT (DD*TT)
#define NOUT ((size_t)BB*TT*CC)

// Workspace layout (bytes) — total 68,032,000 (~64.9 MiB)
#define OFF_H      0ULL
#define SZ_H       ((size_t)BB*GG*TT*DD*4)          // 67108864
#define OFF_PART   (OFF_H + SZ_H)
#define OFF_MUSIG  (OFF_PART + 4096ULL*2*8)
#define OFF_ESQ    (OFF_MUSIG + 32ULL*2*4)
#define OFF_CNT    (OFF_ESQ + (size_t)GG*VV*4)
#define OFF_LOSS   (OFF_CNT + (size_t)GG*VV*4)
#define OFF_EMBH   67180032ULL                       // G*8*4*320*8 halfs = 327680 B
#define OFF_WH     (OFF_EMBH + 327680ULL)            // G*8*4*256*8 halfs = 262144 B
#define OFF_WL     (OFF_WH + 262144ULL)

typedef _Float16 half8   __attribute__((ext_vector_type(8)));
typedef _Float16 half4_t __attribute__((ext_vector_type(4)));
typedef float    f32x4   __attribute__((ext_vector_type(4)));

#define MARGIN 2e-3f
#define CAP 16

#define GLOAD_LDS16(g, l) \
  __builtin_amdgcn_global_load_lds((const __attribute__((address_space(1))) void*)(g), \
                                   (__attribute__((address_space(3))) void*)(l), 16, 0, 0)

// blocks 0..39: esq + emb fp16-hi plane. block 40: init. blocks 41..56: W hi/lo planes.
// emb plane[g][c][hgrp][v][j], k = c*32 + hgrp*4 + (j&3) + 16*(j>>2); W same with o.
__global__ __launch_bounds__(256) void k_emb(const float* __restrict__ emb,
                                             const float* __restrict__ w,
                                             _Float16* __restrict__ embHp,
                                             _Float16* __restrict__ wHp,
                                             _Float16* __restrict__ wLp,
                                             float* __restrict__ esq,
                                             unsigned* __restrict__ counts,
                                             float* __restrict__ loss) {
  int blk = blockIdx.x;
  int tid = threadIdx.x;
  if (blk == 40) {
    for (int i = tid; i < GG*VV; i += 256) counts[i] = 0u;
    if (tid == 0) *loss = 0.0f;
    return;
  }
  if (blk >= 41) {      // W-split blocks
    int wblk = blk - 41;
    int g = wblk >> 3, c = wblk & 7;
    int o = tid;
    const float* wrow = w + (size_t)(g*DD + o)*DD + (c << 5);
    #pragma unroll
    for (int hgrp = 0; hgrp < 4; ++hgrp) {
      float4 f1 = *(const float4*)(wrow + (hgrp << 2));
      float4 f2 = *(const float4*)(wrow + (hgrp << 2) + 16);
      float fv[8] = {f1.x, f1.y, f1.z, f1.w, f2.x, f2.y, f2.z, f2.w};
      half8 vh, vl;
      #pragma unroll
      for (int e = 0; e < 8; ++e) {
        _Float16 hh = (_Float16)fv[e];
        vh[e] = hh;
        vl[e] = (_Float16)(fv[e] - (float)hh);
      }
      size_t base = (((((size_t)(g*8 + c)) << 2) + hgrp) << 8) + o;
      *(half8*)(wHp + (base << 3)) = vh;
      *(half8*)(wLp + (base << 3)) = vl;
    }
    return;
  }
  int g = blk / 20;
  int v0 = (blk % 20) * 16;
  int vl = tid >> 4, dl = tid & 15;
  int v = v0 + vl;
  double sq = 0.0;
  #pragma unroll
  for (int k = 0; k < 16; k++) {
    int d = dl + (k << 4);
    float e = emb[((size_t)v*GG + g)*DD + d];
    sq += (double)e * (double)e;
  }
  #pragma unroll
  for (int m = 1; m < 16; m <<= 1) sq += __shfl_xor(sq, m);
  if (dl == 0) esq[g*VV + v] = (float)sq;

  const int hgrp = dl >> 2, jb = dl & 3;
  #pragma unroll
  for (int c = 0; c < 8; ++c) {
    int k0 = (c << 5) + (hgrp << 2) + jb;
    int k1 = k0 + 16;
    float e0 = emb[((size_t)v*GG + g)*DD + k0];
    float e1 = emb[((size_t)v*GG + g)*DD + k1];
    size_t base = (((size_t)(g*8 + c)*4 + hgrp)*320 + v)*8;
    embHp[base + jb]     = (_Float16)e0;
    embHp[base + jb + 4] = (_Float16)e1;
  }
}

// Conv GEMM, fp16-split 3-pass (bit-identical math to R4/R5): W planes staged
// in LDS (double-buffered, global_load_lds) to amortize L1 traffic across waves.
__global__ __launch_bounds__(256, 2) void k_conv2(const float* __restrict__ x,
                                                  const _Float16* __restrict__ wH,
                                                  const _Float16* __restrict__ wL,
                                                  float* __restrict__ h,
                                                  double* __restrict__ part) {
  __shared__ __align__(16) char BsC[65536];   // [buf][plane 16384 B] H:0/16384, L:32768+...
  __shared__ double r1[4], r2[4];
  const int bid = blockIdx.x;         // 512
  const int bg = bid >> 4, tt = bid & 15;
  const int b = bg >> 1, g = bg & 1;
  const int tid = threadIdx.x;
  const int wv = tid >> 6, lane = tid & 63;
  const int l15 = tid & 15, lh = lane >> 4;
  const int t0w = (tt << 7) + (wv << 5);

  f32x4 acc[2][16];
  #pragma unroll
  for (int tf = 0; tf < 2; ++tf)
    #pragma unroll
    for (int vf = 0; vf < 16; ++vf) acc[tf][vf] = 0.0f;

  const char* WHg = (const char*)(wH + ((size_t)g << 16));
  const char* WLg = (const char*)(wL + ((size_t)g << 16));
  const float* xb0 = x + ((size_t)(b*TT + t0w + l15)*CC + g*DD + (lh << 2));
  const float* xb1 = xb0 + ((size_t)16)*CC;

  // prologue: stage chunk 0, prefetch A chunk 0
  {
    const char* sH = WHg + wv*4096 + lane*16;
    const char* sL = WLg + wv*4096 + lane*16;
    char* dH = BsC + wv*4096;
    char* dL = BsC + 32768 + wv*4096;
    #pragma unroll
    for (int i = 0; i < 4; ++i) {
      GLOAD_LDS16(sH + i*1024, dH + i*1024);
      GLOAD_LDS16(sL + i*1024, dL + i*1024);
    }
  }
  float4 p00 = *(const float4*)(xb0);
  float4 p01 = *(const float4*)(xb0 + 16);
  float4 p10 = *(const float4*)(xb1);
  float4 p11 = *(const float4*)(xb1 + 16);
  __syncthreads();

  int cur = 0;
  #pragma unroll 1
  for (int c = 0; c < 8; ++c) {
    // stage next chunk into other buffer
    if (c < 7) {
      const char* sH = WHg + (size_t)(c + 1)*16384 + wv*4096 + lane*16;
      const char* sL = WLg + (size_t)(c + 1)*16384 + wv*4096 + lane*16;
      char* dH = BsC + (cur ^ 1)*16384 + wv*4096;
      char* dL = BsC + 32768 + (cur ^ 1)*16384 + wv*4096;
      #pragma unroll
      for (int i = 0; i < 4; ++i) {
        GLOAD_LDS16(sH + i*1024, dH + i*1024);
        GLOAD_LDS16(sL + i*1024, dL + i*1024);
      }
    }
    float4 c00 = p00, c01 = p01, c10 = p10, c11 = p11;
    if (c < 7) {
      const int off = (c + 1) << 5;
      p00 = *(const float4*)(xb0 + off);
      p01 = *(const float4*)(xb0 + off + 16);
      p10 = *(const float4*)(xb1 + off);
      p11 = *(const float4*)(xb1 + off + 16);
    }
    half8 ah[2], al[2];
    {
      float fv0[8] = {c00.x, c00.y, c00.z, c00.w, c01.x, c01.y, c01.z, c01.w};
      float fv1[8] = {c10.x, c10.y, c10.z, c10.w, c11.x, c11.y, c11.z, c11.w};
      #pragma unroll
      for (int e = 0; e < 8; ++e) {
        _Float16 h0 = (_Float16)fv0[e];
        ah[0][e] = h0; al[0][e] = (_Float16)(fv0[e] - (float)h0);
        _Float16 h1 = (_Float16)fv1[e];
        ah[1][e] = h1; al[1][e] = (_Float16)(fv1[e] - (float)h1);
      }
    }
    const char* BH = BsC + cur*16384;
    const char* BL = BsC + 32768 + cur*16384;
    #pragma unroll
    for (int vf = 0; vf < 16; ++vf) {
      const int o = (vf << 4) + l15;
      const int bo = ((lh << 8) + o) << 4;
      half8 bh = *(const half8*)(BH + bo);
      half8 bl = *(const half8*)(BL + bo);
      #pragma unroll
      for (int tf = 0; tf < 2; ++tf) {
        acc[tf][vf] = __builtin_amdgcn_mfma_f32_16x16x32_f16(ah[tf], bh, acc[tf][vf], 0, 0, 0);
        acc[tf][vf] = __builtin_amdgcn_mfma_f32_16x16x32_f16(al[tf], bh, acc[tf][vf], 0, 0, 0);
        acc[tf][vf] = __builtin_amdgcn_mfma_f32_16x16x32_f16(ah[tf], bl, acc[tf][vf], 0, 0, 0);
      }
    }
    __syncthreads();
    cur ^= 1;
  }

  // store h + double stats (order identical to R4/R5)
  double s1 = 0.0, s2 = 0.0;
  {
    float* hb = h + (size_t)bg*TT*DD;
    #pragma unroll
    for (int tf = 0; tf < 2; ++tf) {
      #pragma unroll
      for (int reg = 0; reg < 4; ++reg) {
        const int t = t0w + (tf << 4) + (lh << 2) + reg;
        float* hrow = hb + (size_t)t*DD + l15;
        #pragma unroll
        for (int vf = 0; vf < 16; ++vf) {
          float v = acc[tf][vf][reg];
          hrow[vf << 4] = v;
          double dv = (double)v;
          s1 += dv; s2 += dv*dv;
        }
      }
    }
  }
  #pragma unroll
  for (int m = 32; m > 0; m >>= 1) { s1 += __shfl_down(s1, m); s2 += __shfl_down(s2, m); }
  if (lane == 0) { r1[wv] = s1; r2[wv] = s2; }
  __syncthreads();
  if (tid == 0) {
    part[(size_t)bid*2]     = r1[0] + r1[1] + r1[2] + r1[3];
    part[(size_t)bid*2 + 1] = r2[0] + r2[1] + r2[2] + r2[3];
  }
}

__global__ void k_stats(const double* __restrict__ part, float* __restrict__ musig) {
  int i = threadIdx.x;
  if (i < BB*GG) {
    double s1 = 0.0, s2 = 0.0;
    for (int r = 0; r < 16; r++) { s1 += part[(i*16 + r)*2]; s2 += part[(i*16 + r)*2 + 1]; }
    double mu  = s1 / (double)DT;
    double var = s2 / (double)DT - mu*mu;
    double rs  = 1.0 / sqrt(var + 1e-5);
    musig[i*2]     = (float)mu;
    musig[i*2 + 1] = (float)rs;
  }
}

// MFMA VQ: hi-plane-only scoring (ordering, MARGIN=2e-3) + LDS-staged B (dbuf)
// + wave-parallel double-precision exact recheck + ILP-batched epilogue.
__global__ __launch_bounds__(256, 2) void k_vq2(const float* __restrict__ h,
                                                const float* __restrict__ musig,
                                                const float* __restrict__ gn_w,
                                                const float* __restrict__ gn_b,
                                                const _Float16* __restrict__ embH,
                                                const float* __restrict__ esq,
                                                const float* __restrict__ emb,
                                                float* __restrict__ out,
                                                unsigned* __restrict__ counts,
                                                float* __restrict__ loss) {
  __shared__ __align__(16) char smem[43008];
  // [0,40960): B double-buffer (2 x 20480 B). Epilogue overlay (after K-loop):
  float*  esqs    = (float*)smem;                // 320 f
  int*    candcnt = (int*)(smem + 1280);         // 128
  int*    bestv   = (int*)(smem + 1792);         // 128
  int*    slowl   = (int*)(smem + 2304);         // 128
  int*    nslow   = (int*)(smem + 2816);
  unsigned short* cand = (unsigned short*)(smem + 2832);  // [128][CAP=16]
  float*  redf    = (float*)(smem + 6944);       // 4
  float*  gnws    = (float*)(smem + 40960);      // 256 f (outside overlay + dbuf)
  float*  gnbs    = (float*)(smem + 41984);      // 256 f

  const int bid = blockIdx.x;        // 512 blocks
  const int bg  = bid >> 4;
  const int t0  = (bid & 15) << 7;
  const int b = bg >> 1, g = bg & 1;
  const int tid = threadIdx.x;
  const int lane = tid & 63, wv = tid >> 6;
  const int l15 = tid & 15, lh = lane >> 4;
  const float mu = musig[bg*2], rs = musig[bg*2 + 1];
  const float* hb = h + ((size_t)bg*TT + t0)*DD;

  gnws[tid] = gn_w[g*DD + tid];
  gnbs[tid] = gn_b[g*DD + tid];

  f32x4 acc[2][20];
  #pragma unroll
  for (int tf = 0; tf < 2; ++tf)
    #pragma unroll
    for (int vf = 0; vf < 20; ++vf) acc[tf][vf] = 0.0f;

  const char* gBH = (const char*)(embH + (size_t)(g*8)*10240);
  const float* gwp = gn_w + g*DD;
  const float* gbp = gn_b + g*DD;

  const float* hb0 = hb + (size_t)((wv << 5) + l15)*DD + (lh << 2);
  const float* hb1 = hb0 + ((size_t)16)*DD;

  // prologue: stage chunk 0 B, prefetch A chunk 0
  {
    const char* sB = gBH + wv*5120 + lane*16;
    char* dB = smem + wv*5120;
    #pragma unroll
    for (int i = 0; i < 5; ++i) GLOAD_LDS16(sB + i*1024, dB + i*1024);
  }
  float4 p00 = *(const float4*)(hb0);
  float4 p01 = *(const float4*)(hb0 + 16);
  float4 p10 = *(const float4*)(hb1);
  float4 p11 = *(const float4*)(hb1 + 16);
  __syncthreads();

  int cur = 0;
  #pragma unroll 1
  for (int c = 0; c < 8; ++c) {
    if (c < 7) {
      const char* sB = gBH + (size_t)(c + 1)*20480 + wv*5120 + lane*16;
      char* dB = smem + (cur ^ 1)*20480 + wv*5120;
      #pragma unroll
      for (int i = 0; i < 5; ++i) GLOAD_LDS16(sB + i*1024, dB + i*1024);
    }
    float4 c00 = p00, c01 = p01, c10 = p10, c11 = p11;
    if (c < 7) {
      const int off = (c + 1) << 5;
      p00 = *(const float4*)(hb0 + off);
      p01 = *(const float4*)(hb0 + off + 16);
      p10 = *(const float4*)(hb1 + off);
      p11 = *(const float4*)(hb1 + off + 16);
    }
    const int c32 = c << 5;
    half8 ah[2];
    {
      float4 w1 = *(const float4*)(gwp + c32 + (lh << 2));
      float4 w2 = *(const float4*)(gwp + c32 + (lh << 2) + 16);
      float4 b1 = *(const float4*)(gbp + c32 + (lh << 2));
      float4 b2 = *(const float4*)(gbp + c32 + (lh << 2) + 16);
      float wv_[8] = {w1.x, w1.y, w1.z, w1.w, w2.x, w2.y, w2.z, w2.w};
      float bv_[8] = {b1.x, b1.y, b1.z, b1.w, b2.x, b2.y, b2.z, b2.w};
      float fv0[8] = {c00.x, c00.y, c00.z, c00.w, c01.x, c01.y, c01.z, c01.w};
      float fv1[8] = {c10.x, c10.y, c10.z, c10.w, c11.x, c11.y, c11.z, c11.w};
      #pragma unroll
      for (int e = 0; e < 8; ++e) {
        float z0 = __fmul_rn(__fsub_rn(fv0[e], mu), rs);
        z0 = __fadd_rn(__fmul_rn(z0, wv_[e]), bv_[e]);
        ah[0][e] = (_Float16)z0;
        float z1 = __fmul_rn(__fsub_rn(fv1[e], mu), rs);
        z1 = __fadd_rn(__fmul_rn(z1, wv_[e]), bv_[e]);
        ah[1][e] = (_Float16)z1;
      }
    }
    const char* BH = smem + cur*20480;
    #pragma unroll
    for (int vf = 0; vf < 20; ++vf) {
      const int v = (vf << 4) + l15;
      half8 bh = *(const half8*)(BH + ((lh*320 + v) << 4));
      #pragma unroll
      for (int tf = 0; tf < 2; ++tf)
        acc[tf][vf] = __builtin_amdgcn_mfma_f32_16x16x32_f16(ah[tf], bh, acc[tf][vf], 0, 0, 0);
    }
    __syncthreads();
    cur ^= 1;
  }

  // ---- epilogue: overlay init ----
  if (tid < 160) { esqs[tid] = esq[g*VV + tid]; esqs[tid + 160] = esq[g*VV + tid + 160]; }
  if (tid < 128) { candcnt[tid] = 0; bestv[tid] = -1; }
  if (tid == 0) *nslow = 0;
  __syncthreads();

  // selection: y = esq - 2c'; candidates within MARGIN of row min
  #pragma unroll
  for (int tf = 0; tf < 2; ++tf) {
    #pragma unroll
    for (int reg = 0; reg < 4; ++reg) {
      int row = (wv << 5) + (tf << 4) + (lh << 2) + reg;
      float y[20]; float mn = 3.4e38f;
      #pragma unroll
      for (int vf = 0; vf < 20; ++vf) {
        y[vf] = fmaf(-2.0f, acc[tf][vf][reg], esqs[(vf << 4) + l15]);
        mn = fminf(mn, y[vf]);
      }
      #pragma unroll
      for (int m = 1; m < 16; m <<= 1) mn = fminf(mn, __shfl_xor(mn, m));
      float thr = mn + MARGIN;
      #pragma unroll
      for (int vf = 0; vf < 20; ++vf) {
        if (y[vf] <= thr) {
          int pos = atomicAdd(&candcnt[row], 1);
          if (pos < CAP) cand[row*CAP + pos] = (unsigned short)((vf << 4) + l15);
        }
      }
    }
  }
  __syncthreads();
  if (tid < 128) {
    int cnt = candcnt[tid];
    if (cnt == 1) bestv[tid] = cand[tid*CAP];
    else { int p = atomicAdd(nslow, 1); slowl[p] = tid; }
  }
  __syncthreads();

  // slow path: wave-parallel double-precision recheck, rows striped across waves
  const int ns = *nslow;
  for (int i = wv; i < ns; i += 4) {
    const int row = slowl[i];
    // exact z for d = lane*4 .. lane*4+3
    float4 hx  = *(const float4*)(hb + (size_t)row*DD + (lane << 2));
    float4 gw4 = *(const float4*)(gnws + (lane << 2));
    float4 gb4 = *(const float4*)(gnbs + (lane << 2));
    float hv[4] = {hx.x, hx.y, hx.z, hx.w};
    float gwv[4] = {gw4.x, gw4.y, gw4.z, gw4.w};
    float gbv[4] = {gb4.x, gb4.y, gb4.z, gb4.w};
    float zf[4];
    #pragma unroll
    for (int e = 0; e < 4; ++e) {
      float z = __fmul_rn(__fsub_rn(hv[e], mu), rs);
      zf[e] = __fadd_rn(__fmul_rn(z, gwv[e]), gbv[e]);
    }
    int cnt = candcnt[row];
    double bd = 1e300; int bvv = 0x7fffffff;
    if (cnt <= CAP) {
      for (int ci = 0; ci < cnt; ++ci) {
        int v = cand[row*CAP + ci];
        float4 ev = *(const float4*)(emb + ((size_t)v*GG + g)*DD + (lane << 2));
        float evv[4] = {ev.x, ev.y, ev.z, ev.w};
        double s = 0.0;
        #pragma unroll
        for (int e = 0; e < 4; ++e) {
          double df = (double)zf[e] - (double)evv[e];
          s += df*df;
        }
        #pragma unroll
        for (int m = 32; m > 0; m >>= 1) s += __shfl_down(s, m);
        s = __shfl(s, 0);
        if (s < bd || (s == bd && v < bvv)) { bd = s; bvv = v; }
      }
    } else {
      for (int v = 0; v < VV; ++v) {
        float4 ev = *(const float4*)(emb + ((size_t)v*GG + g)*DD + (lane << 2));
        float evv[4] = {ev.x, ev.y, ev.z, ev.w};
        double s = 0.0;
        #pragma unroll
        for (int e = 0; e < 4; ++e) {
          double df = (double)zf[e] - (double)evv[e];
          s += df*df;
        }
        #pragma unroll
        for (int m = 32; m > 0; m >>= 1) s += __shfl_down(s, m);
        s = __shfl(s, 0);
        if (s < bd) { bd = s; bvv = v; }
      }
    }
    if (lane == 0) bestv[row] = bvv;
  }
  __syncthreads();

  if (tid < 128) atomicAdd(&counts[g*VV + bestv[tid]], 1u);

  // Phase 3: x_out = selected embedding; loss partial — 8-row batched for ILP
  float lp = 0.0f;
  float* ob = out + (size_t)(b*TT + t0)*CC + g*DD + tid;
  const float gw = gnws[tid], gb2 = gnbs[tid];
  #pragma unroll 1
  for (int r0 = 0; r0 < 128; r0 += 8) {
    int vv[8]; float ee[8], hh[8];
    #pragma unroll
    for (int j = 0; j < 8; ++j) vv[j] = bestv[r0 + j];
    #pragma unroll
    for (int j = 0; j < 8; ++j) ee[j] = emb[((size_t)vv[j]*GG + g)*DD + tid];
    #pragma unroll
    for (int j = 0; j < 8; ++j) hh[j] = hb[(size_t)(r0 + j)*DD + tid];
    #pragma unroll
    for (int j = 0; j < 8; ++j) {
      float z = __fmul_rn(__fsub_rn(hh[j], mu), rs);
      z = __fadd_rn(__fmul_rn(z, gw), gb2);
      float df = ee[j] - z;
      lp = fmaf(df, df, lp);
      ob[(size_t)(r0 + j)*CC] = ee[j];
    }
  }
  #pragma unroll
  for (int m = 32; m > 0; m >>= 1) lp += __shfl_down(lp, m);
  if (lane == 0) redf[wv] = lp;
  __syncthreads();
  if (tid == 0) atomicAdd(loss, redf[0] + redf[1] + redf[2] + redf[3]);
}

__global__ __launch_bounds__(256) void k_final(const unsigned* __restrict__ counts,
                                               const float* __restrict__ loss,
                                               float* __restrict__ out) {
  __shared__ float sd[256];
  int tid = threadIdx.x;
  float perp = 0.0f;
  for (int g = 0; g < GG; g++) {
    float p1 = 0.0f;
    for (int v = tid; v < VV; v += 256) {
      float p = (float)counts[g*VV + v] / 32768.0f;
      p1 += p * logf(p + 1e-7f);
    }
    sd[tid] = p1;
    __syncthreads();
    for (int s = 128; s > 0; s >>= 1) {
      if (tid < s) sd[tid] += sd[tid + s];
      __syncthreads();
    }
    if (tid == 0) perp += expf(-sd[0]);
    __syncthreads();
  }
  if (tid == 0) {
    out[NOUT]     = 1.25f * (*loss) / (float)NOUT;
    out[NOUT + 1] = perp;
  }
}

extern "C" void kernel_launch(void* const* d_in, const int* in_sizes, int n_in,
                              void* d_out, int out_size, void* d_ws, size_t ws_size,
                              hipStream_t stream) {
  const float* x   = (const float*)d_in[0];
  const float* cw  = (const float*)d_in[1];
  const float* gnw = (const float*)d_in[2];
  const float* gnb = (const float*)d_in[3];
  const float* emb = (const float*)d_in[4];
  float* out = (float*)d_out;
  char* ws = (char*)d_ws;
  float*     h      = (float*)(ws + OFF_H);
  double*    part   = (double*)(ws + OFF_PART);
  float*     musig  = (float*)(ws + OFF_MUSIG);
  float*     esq    = (float*)(ws + OFF_ESQ);
  unsigned*  counts = (unsigned*)(ws + OFF_CNT);
  float*     loss   = (float*)(ws + OFF_LOSS);
  _Float16*  embH   = (_Float16*)(ws + OFF_EMBH);
  _Float16*  wH     = (_Float16*)(ws + OFF_WH);
  _Float16*  wL     = (_Float16*)(ws + OFF_WL);

  hipLaunchKernelGGL(k_emb,   dim3(57),   dim3(256), 0, stream,
                     emb, cw, embH, wH, wL, esq, counts, loss);
  hipLaunchKernelGGL(k_conv2, dim3(512),  dim3(256), 0, stream, x, wH, wL, h, part);
  hipLaunchKernelGGL(k_stats, dim3(1),    dim3(32),  0, stream, part, musig);
  hipLaunchKernelGGL(k_vq2,   dim3(512),  dim3(256), 0, stream,
                     h, musig, gnw, gnb, embH, esq, emb, out, counts, loss);
  hipLaunchKernelGGL(k_final, dim3(1),    dim3(256), 0, stream, counts, loss, out);
}

// Round 7
// 99.293 us; speedup vs baseline: 1.4697x; 1.0454x over previous
//
#include <hip/hip_runtime.h>
#include <math.h>

// Problem constants
#define BB 16
#define TT 2048
#define CC 512
#define GG 2
#define DD 256      // C/G
#define VV 320
#define DT (DD*TT)
#define NOUT ((size_t)BB*TT*CC)

// Workspace layout (bytes)
#define OFF_H      0ULL
#define SZ_H       ((size_t)BB*GG*TT*DD*4)          // 67108864
#define OFF_PART   (OFF_H + SZ_H)
#define OFF_MUSIG  (OFF_PART + 4096ULL*2*8)
#define OFF_ESQ    (OFF_MUSIG + 32ULL*2*4)
#define OFF_CNT    (OFF_ESQ + (size_t)GG*VV*4)
#define OFF_LOSS   (OFF_CNT + (size_t)GG*VV*4)
#define OFF_EMBH   67180032ULL                       // G*8*4*320*8 halfs = 327680 B
#define OFF_WH     (OFF_EMBH + 327680ULL)            // G*8*4*256*8 halfs = 262144 B
#define OFF_WL     (OFF_WH + 262144ULL)

typedef _Float16 half8   __attribute__((ext_vector_type(8)));
typedef float    f32x4   __attribute__((ext_vector_type(4)));

#define MARGIN 2e-3f
#define CAP 16

#define GLOAD_LDS16(g, l) \
  __builtin_amdgcn_global_load_lds((const __attribute__((address_space(1))) void*)(g), \
                                   (__attribute__((address_space(3))) void*)(l), 16, 0, 0)

// blocks 0..39: esq + emb fp16-hi plane. block 40: init. blocks 41..56: W hi/lo planes.
__global__ __launch_bounds__(256) void k_emb(const float* __restrict__ emb,
                                             const float* __restrict__ w,
                                             _Float16* __restrict__ embHp,
                                             _Float16* __restrict__ wHp,
                                             _Float16* __restrict__ wLp,
                                             float* __restrict__ esq,
                                             unsigned* __restrict__ counts,
                                             float* __restrict__ loss) {
  int blk = blockIdx.x;
  int tid = threadIdx.x;
  if (blk == 40) {
    for (int i = tid; i < GG*VV; i += 256) counts[i] = 0u;
    if (tid == 0) *loss = 0.0f;
    return;
  }
  if (blk >= 41) {
    int wblk = blk - 41;
    int g = wblk >> 3, c = wblk & 7;
    int o = tid;
    const float* wrow = w + (size_t)(g*DD + o)*DD + (c << 5);
    #pragma unroll
    for (int hgrp = 0; hgrp < 4; ++hgrp) {
      float4 f1 = *(const float4*)(wrow + (hgrp << 2));
      float4 f2 = *(const float4*)(wrow + (hgrp << 2) + 16);
      float fv[8] = {f1.x, f1.y, f1.z, f1.w, f2.x, f2.y, f2.z, f2.w};
      half8 vh, vl;
      #pragma unroll
      for (int e = 0; e < 8; ++e) {
        _Float16 hh = (_Float16)fv[e];
        vh[e] = hh;
        vl[e] = (_Float16)(fv[e] - (float)hh);
      }
      size_t base = (((((size_t)(g*8 + c)) << 2) + hgrp) << 8) + o;
      *(half8*)(wHp + (base << 3)) = vh;
      *(half8*)(wLp + (base << 3)) = vl;
    }
    return;
  }
  int g = blk / 20;
  int v0 = (blk % 20) * 16;
  int vl = tid >> 4, dl = tid & 15;
  int v = v0 + vl;
  double sq = 0.0;
  #pragma unroll
  for (int k = 0; k < 16; k++) {
    int d = dl + (k << 4);
    float e = emb[((size_t)v*GG + g)*DD + d];
    sq += (double)e * (double)e;
  }
  #pragma unroll
  for (int m = 1; m < 16; m <<= 1) sq += __shfl_xor(sq, m);
  if (dl == 0) esq[g*VV + v] = (float)sq;

  const int hgrp = dl >> 2, jb = dl & 3;
  #pragma unroll
  for (int c = 0; c < 8; ++c) {
    int k0 = (c << 5) + (hgrp << 2) + jb;
    int k1 = k0 + 16;
    float e0 = emb[((size_t)v*GG + g)*DD + k0];
    float e1 = emb[((size_t)v*GG + g)*DD + k1];
    size_t base = (((size_t)(g*8 + c)*4 + hgrp)*320 + v)*8;
    embHp[base + jb]     = (_Float16)e0;
    embHp[base + jb + 4] = (_Float16)e1;
  }
}

// Conv GEMM, fp16-split 3-pass (bit-identical math): counted-vmcnt pipeline.
__global__ __launch_bounds__(256, 2) void k_conv2(const float* __restrict__ x,
                                                  const _Float16* __restrict__ wH,
                                                  const _Float16* __restrict__ wL,
                                                  float* __restrict__ h,
                                                  double* __restrict__ part) {
  __shared__ __align__(16) char BsC[65536];   // [buf][H 16384 | at +32768 L 16384]
  __shared__ double r1[4], r2[4];
  const int bid = blockIdx.x;         // 512
  const int bg = bid >> 4, tt = bid & 15;
  const int b = bg >> 1, g = bg & 1;
  const int tid = threadIdx.x;
  const int wv = tid >> 6, lane = tid & 63;
  const int l15 = tid & 15, lh = lane >> 4;
  const int t0w = (tt << 7) + (wv << 5);

  f32x4 acc[2][16];
  #pragma unroll
  for (int tf = 0; tf < 2; ++tf)
    #pragma unroll
    for (int vf = 0; vf < 16; ++vf) acc[tf][vf] = 0.0f;

  const char* WHg = (const char*)(wH + ((size_t)g << 16));
  const char* WLg = (const char*)(wL + ((size_t)g << 16));
  const float* xb0 = x + ((size_t)(b*TT + t0w + l15)*CC + g*DD + (lh << 2));
  const float* xb1 = xb0 + ((size_t)16)*CC;

  // prologue: stage chunk 0 (8 lds-loads), prefetch A chunk 0 (4 loads)
  {
    const char* sH = WHg + wv*4096 + lane*16;
    const char* sL = WLg + wv*4096 + lane*16;
    char* dH = BsC + wv*4096;
    char* dL = BsC + 32768 + wv*4096;
    #pragma unroll
    for (int i = 0; i < 4; ++i) {
      GLOAD_LDS16(sH + i*1024, dH + i*1024);
      GLOAD_LDS16(sL + i*1024, dL + i*1024);
    }
  }
  float4 p00 = *(const float4*)(xb0);
  float4 p01 = *(const float4*)(xb0 + 16);
  float4 p10 = *(const float4*)(xb1);
  float4 p11 = *(const float4*)(xb1 + 16);

  int cur = 0;
  #pragma unroll 1
  for (int c = 0; c < 8; ++c) {
    if (c < 7) {
      const char* sH = WHg + (size_t)(c + 1)*16384 + wv*4096 + lane*16;
      const char* sL = WLg + (size_t)(c + 1)*16384 + wv*4096 + lane*16;
      char* dH = BsC + (cur ^ 1)*16384 + wv*4096;
      char* dL = BsC + 32768 + (cur ^ 1)*16384 + wv*4096;
      #pragma unroll
      for (int i = 0; i < 4; ++i) {
        GLOAD_LDS16(sH + i*1024, dH + i*1024);
        GLOAD_LDS16(sL + i*1024, dL + i*1024);
      }
      // outstanding: [stage_c 8][A_c 4][stage_{c+1} 8] -> drain stage_c
      asm volatile("s_waitcnt vmcnt(12)" ::: "memory");
    } else {
      // outstanding: [stage_7 8][A_7 4] -> drain stage_7
      asm volatile("s_waitcnt vmcnt(4)" ::: "memory");
    }
    __builtin_amdgcn_s_barrier();

    float4 c00 = p00, c01 = p01, c10 = p10, c11 = p11;
    if (c < 7) {
      const int off = (c + 1) << 5;
      p00 = *(const float4*)(xb0 + off);
      p01 = *(const float4*)(xb0 + off + 16);
      p10 = *(const float4*)(xb1 + off);
      p11 = *(const float4*)(xb1 + off + 16);
    }
    half8 ah[2], al[2];
    {
      float fv0[8] = {c00.x, c00.y, c00.z, c00.w, c01.x, c01.y, c01.z, c01.w};
      float fv1[8] = {c10.x, c10.y, c10.z, c10.w, c11.x, c11.y, c11.z, c11.w};
      #pragma unroll
      for (int e = 0; e < 8; ++e) {
        _Float16 h0 = (_Float16)fv0[e];
        ah[0][e] = h0; al[0][e] = (_Float16)(fv0[e] - (float)h0);
        _Float16 h1 = (_Float16)fv1[e];
        ah[1][e] = h1; al[1][e] = (_Float16)(fv1[e] - (float)h1);
      }
    }
    const char* BH = BsC + cur*16384;
    const char* BL = BsC + 32768 + cur*16384;
    #pragma unroll
    for (int vf = 0; vf < 16; ++vf) {
      const int o = (vf << 4) + l15;
      const int bo = ((lh << 8) + o) << 4;
      half8 bh = *(const half8*)(BH + bo);
      half8 bl = *(const half8*)(BL + bo);
      #pragma unroll
      for (int tf = 0; tf < 2; ++tf) {
        acc[tf][vf] = __builtin_amdgcn_mfma_f32_16x16x32_f16(ah[tf], bh, acc[tf][vf], 0, 0, 0);
        acc[tf][vf] = __builtin_amdgcn_mfma_f32_16x16x32_f16(al[tf], bh, acc[tf][vf], 0, 0, 0);
        acc[tf][vf] = __builtin_amdgcn_mfma_f32_16x16x32_f16(ah[tf], bl, acc[tf][vf], 0, 0, 0);
      }
    }
    __builtin_amdgcn_s_barrier();
    cur ^= 1;
  }

  // store h + double stats (order identical to R4-R6)
  double s1 = 0.0, s2 = 0.0;
  {
    float* hb = h + (size_t)bg*TT*DD;
    #pragma unroll
    for (int tf = 0; tf < 2; ++tf) {
      #pragma unroll
      for (int reg = 0; reg < 4; ++reg) {
        const int t = t0w + (tf << 4) + (lh << 2) + reg;
        float* hrow = hb + (size_t)t*DD + l15;
        #pragma unroll
        for (int vf = 0; vf < 16; ++vf) {
          float v = acc[tf][vf][reg];
          hrow[vf << 4] = v;
          double dv = (double)v;
          s1 += dv; s2 += dv*dv;
        }
      }
    }
  }
  #pragma unroll
  for (int m = 32; m > 0; m >>= 1) { s1 += __shfl_down(s1, m); s2 += __shfl_down(s2, m); }
  if (lane == 0) { r1[wv] = s1; r2[wv] = s2; }
  __syncthreads();
  if (tid == 0) {
    part[(size_t)bid*2]     = r1[0] + r1[1] + r1[2] + r1[3];
    part[(size_t)bid*2 + 1] = r2[0] + r2[1] + r2[2] + r2[3];
  }
}

__global__ void k_stats(const double* __restrict__ part, float* __restrict__ musig) {
  int i = threadIdx.x;
  if (i < BB*GG) {
    double s1 = 0.0, s2 = 0.0;
    for (int r = 0; r < 16; r++) { s1 += part[(i*16 + r)*2]; s2 += part[(i*16 + r)*2 + 1]; }
    double mu  = s1 / (double)DT;
    double var = s2 / (double)DT - mu*mu;
    double rs  = 1.0 / sqrt(var + 1e-5);
    musig[i*2]     = (float)mu;
    musig[i*2 + 1] = (float)rs;
  }
}

// MFMA VQ: 64 rows x 320 v per block (1024 blocks), counted-vmcnt pipeline,
// hi-plane scoring + candidate margin + double recheck; loss from ze2 + ymin.
__global__ __launch_bounds__(256, 3) void k_vq2(const float* __restrict__ h,
                                                const float* __restrict__ musig,
                                                const float* __restrict__ gn_w,
                                                const float* __restrict__ gn_b,
                                                const _Float16* __restrict__ embH,
                                                const float* __restrict__ esq,
                                                const float* __restrict__ emb,
                                                float* __restrict__ out,
                                                unsigned* __restrict__ counts,
                                                float* __restrict__ loss) {
  __shared__ __align__(16) char smem[40960];   // B dbuf 2 x 20480; overlay after K-loop
  float*  esqs    = (float*)smem;                // 320 f
  int*    candcnt = (int*)(smem + 1280);         // 64
  int*    bestv   = (int*)(smem + 1536);         // 64
  int*    slowl   = (int*)(smem + 1792);         // 64
  int*    nslow   = (int*)(smem + 2048);
  float*  ze2s    = (float*)(smem + 2112);       // 64
  float*  ymins   = (float*)(smem + 2368);       // 64
  float*  lossrow = (float*)(smem + 2624);       // 64
  unsigned short* cand = (unsigned short*)(smem + 2880);  // [64][CAP]

  const int bid = blockIdx.x;        // 1024 blocks
  const int bg  = bid >> 5;
  const int t0  = (bid & 31) << 6;
  const int b = bg >> 1, g = bg & 1;
  const int tid = threadIdx.x;
  const int lane = tid & 63, wv = tid >> 6;
  const int l15 = tid & 15, lh = lane >> 4;
  const float mu = musig[bg*2], rs = musig[bg*2 + 1];
  const float* hb = h + ((size_t)bg*TT + t0)*DD;

  f32x4 acc[20];
  #pragma unroll
  for (int vf = 0; vf < 20; ++vf) acc[vf] = 0.0f;

  const char* gBH = (const char*)(embH + (size_t)(g*8)*10240);
  const float* gwp = gn_w + g*DD;
  const float* gbp = gn_b + g*DD;
  const float* hb0 = hb + (size_t)((wv << 4) + l15)*DD + (lh << 2);

  // prologue: stage chunk 0 (5 lds-loads), prefetch gn+A chunk 0 (6 loads)
  {
    const char* sB = gBH + wv*5120 + lane*16;
    char* dB = smem + wv*5120;
    #pragma unroll
    for (int i = 0; i < 5; ++i) GLOAD_LDS16(sB + i*1024, dB + i*1024);
  }
  float4 gw1 = *(const float4*)(gwp + (lh << 2));
  float4 gw2 = *(const float4*)(gwp + (lh << 2) + 16);
  float4 gb1 = *(const float4*)(gbp + (lh << 2));
  float4 gb2 = *(const float4*)(gbp + (lh << 2) + 16);
  float4 pa0 = *(const float4*)(hb0);
  float4 pa1 = *(const float4*)(hb0 + 16);

  float ze2acc = 0.0f;
  int cur = 0;
  #pragma unroll 1
  for (int c = 0; c < 8; ++c) {
    if (c < 7) {
      const char* sB = gBH + (size_t)(c + 1)*20480 + wv*5120 + lane*16;
      char* dB = smem + (cur ^ 1)*20480 + wv*5120;
      #pragma unroll
      for (int i = 0; i < 5; ++i) GLOAD_LDS16(sB + i*1024, dB + i*1024);
      // outstanding: [stage_c 5][gnA_c 6][stage_{c+1} 5] -> drain stage_c
      asm volatile("s_waitcnt vmcnt(11)" ::: "memory");
    } else {
      // outstanding: [stage_7 5][gnA_7 6] -> drain stage_7
      asm volatile("s_waitcnt vmcnt(6)" ::: "memory");
    }
    __builtin_amdgcn_s_barrier();

    float4 a0 = pa0, a1 = pa1, w1 = gw1, w2 = gw2, b1 = gb1, b2 = gb2;
    if (c < 7) {
      const int off = (c + 1) << 5;
      gw1 = *(const float4*)(gwp + off + (lh << 2));
      gw2 = *(const float4*)(gwp + off + (lh << 2) + 16);
      gb1 = *(const float4*)(gbp + off + (lh << 2));
      gb2 = *(const float4*)(gbp + off + (lh << 2) + 16);
      pa0 = *(const float4*)(hb0 + off);
      pa1 = *(const float4*)(hb0 + off + 16);
    }
    half8 ah;
    {
      float fv[8]  = {a0.x, a0.y, a0.z, a0.w, a1.x, a1.y, a1.z, a1.w};
      float wv_[8] = {w1.x, w1.y, w1.z, w1.w, w2.x, w2.y, w2.z, w2.w};
      float bv_[8] = {b1.x, b1.y, b1.z, b1.w, b2.x, b2.y, b2.z, b2.w};
      #pragma unroll
      for (int e = 0; e < 8; ++e) {
        float z = __fmul_rn(__fsub_rn(fv[e], mu), rs);
        z = __fadd_rn(__fmul_rn(z, wv_[e]), bv_[e]);
        ah[e] = (_Float16)z;
        ze2acc = fmaf(z, z, ze2acc);
      }
    }
    const char* BH = smem + cur*20480;
    #pragma unroll
    for (int vf = 0; vf < 20; ++vf) {
      const int v = (vf << 4) + l15;
      half8 bh = *(const half8*)(BH + ((lh*320 + v) << 4));
      acc[vf] = __builtin_amdgcn_mfma_f32_16x16x32_f16(ah, bh, acc[vf], 0, 0, 0);
    }
    __builtin_amdgcn_s_barrier();
    cur ^= 1;
  }
  __syncthreads();

  // ---- epilogue: overlay init + ze2 ----
  if (tid < 160) { esqs[tid] = esq[g*VV + tid]; esqs[tid + 160] = esq[g*VV + tid + 160]; }
  if (tid < 64) { candcnt[tid] = 0; bestv[tid] = -1; }
  if (tid == 0) *nslow = 0;
  {
    float s = ze2acc;
    s += __shfl_down(s, 32);
    s += __shfl_down(s, 16);
    if (lane < 16) ze2s[(wv << 4) + l15] = s;
  }
  __syncthreads();

  // selection: y = esq - 2c'; candidates within MARGIN of row min
  #pragma unroll
  for (int reg = 0; reg < 4; ++reg) {
    int row = (wv << 4) + (lh << 2) + reg;
    float y[20]; float mn = 3.4e38f;
    #pragma unroll
    for (int vf = 0; vf < 20; ++vf) {
      y[vf] = fmaf(-2.0f, acc[vf][reg], esqs[(vf << 4) + l15]);
      mn = fminf(mn, y[vf]);
    }
    #pragma unroll
    for (int m = 1; m < 16; m <<= 1) mn = fminf(mn, __shfl_xor(mn, m));
    if (l15 == 0) ymins[row] = mn;
    float thr = mn + MARGIN;
    #pragma unroll
    for (int vf = 0; vf < 20; ++vf) {
      if (y[vf] <= thr) {
        int pos = atomicAdd(&candcnt[row], 1);
        if (pos < CAP) cand[row*CAP + pos] = (unsigned short)((vf << 4) + l15);
      }
    }
  }
  __syncthreads();
  if (tid < 64) {
    int cnt = candcnt[tid];
    if (cnt == 1) {
      bestv[tid] = cand[tid*CAP];
      lossrow[tid] = ze2s[tid] + ymins[tid];
    } else {
      int p = atomicAdd(nslow, 1); slowl[p] = tid;
    }
  }
  __syncthreads();

  // slow path: wave-parallel double-precision recheck
  const int ns = *nslow;
  for (int i = wv; i < ns; i += 4) {
    const int row = slowl[i];
    float4 hx  = *(const float4*)(hb + (size_t)row*DD + (lane << 2));
    float4 gw4 = *(const float4*)(gwp + (lane << 2));
    float4 gb4 = *(const float4*)(gbp + (lane << 2));
    float hv[4] = {hx.x, hx.y, hx.z, hx.w};
    float gwv[4] = {gw4.x, gw4.y, gw4.z, gw4.w};
    float gbv[4] = {gb4.x, gb4.y, gb4.z, gb4.w};
    float zf[4];
    #pragma unroll
    for (int e = 0; e < 4; ++e) {
      float z = __fmul_rn(__fsub_rn(hv[e], mu), rs);
      zf[e] = __fadd_rn(__fmul_rn(z, gwv[e]), gbv[e]);
    }
    int cnt = candcnt[row];
    double bd = 1e300; int bvv = 0x7fffffff;
    if (cnt <= CAP) {
      for (int ci = 0; ci < cnt; ++ci) {
        int v = cand[row*CAP + ci];
        float4 ev = *(const float4*)(emb + ((size_t)v*GG + g)*DD + (lane << 2));
        float evv[4] = {ev.x, ev.y, ev.z, ev.w};
        double s = 0.0;
        #pragma unroll
        for (int e = 0; e < 4; ++e) {
          double df = (double)zf[e] - (double)evv[e];
          s += df*df;
        }
        #pragma unroll
        for (int m = 32; m > 0; m >>= 1) s += __shfl_down(s, m);
        s = __shfl(s, 0);
        if (s < bd || (s == bd && v < bvv)) { bd = s; bvv = v; }
      }
    } else {
      for (int v = 0; v < VV; ++v) {
        float4 ev = *(const float4*)(emb + ((size_t)v*GG + g)*DD + (lane << 2));
        float evv[4] = {ev.x, ev.y, ev.z, ev.w};
        double s = 0.0;
        #pragma unroll
        for (int e = 0; e < 4; ++e) {
          double df = (double)zf[e] - (double)evv[e];
          s += df*df;
        }
        #pragma unroll
        for (int m = 32; m > 0; m >>= 1) s += __shfl_down(s, m);
        s = __shfl(s, 0);
        if (s < bd) { bd = s; bvv = v; }
      }
    }
    if (lane == 0) { bestv[row] = bvv; lossrow[row] = (float)bd; }
  }
  __syncthreads();

  if (tid < 64) atomicAdd(&counts[g*VV + bestv[tid]], 1u);
  if (wv == 0) {
    float s = lossrow[lane];
    #pragma unroll
    for (int m = 32; m > 0; m >>= 1) s += __shfl_down(s, m);
    if (lane == 0) atomicAdd(loss, s);
  }

  // Phase 3: x_out = selected embedding (no h re-read), 8-row batches for ILP
  float* ob = out + (size_t)(b*TT + t0)*CC + g*DD + tid;
  #pragma unroll 1
  for (int r0 = 0; r0 < 64; r0 += 8) {
    int vv[8]; float ee[8];
    #pragma unroll
    for (int j = 0; j < 8; ++j) vv[j] = bestv[r0 + j];
    #pragma unroll
    for (int j = 0; j < 8; ++j) ee[j] = emb[((size_t)vv[j]*GG + g)*DD + tid];
    #pragma unroll
    for (int j = 0; j < 8; ++j) ob[(size_t)(r0 + j)*CC] = ee[j];
  }
}

__global__ __launch_bounds__(256) void k_final(const unsigned* __restrict__ counts,
                                               const float* __restrict__ loss,
                                               float* __restrict__ out) {
  __shared__ float sd[256];
  int tid = threadIdx.x;
  float perp = 0.0f;
  for (int g = 0; g < GG; g++) {
    float p1 = 0.0f;
    for (int v = tid; v < VV; v += 256) {
      float p = (float)counts[g*VV + v] / 32768.0f;
      p1 += p * logf(p + 1e-7f);
    }
    sd[tid] = p1;
    __syncthreads();
    for (int s = 128; s > 0; s >>= 1) {
      if (tid < s) sd[tid] += sd[tid + s];
      __syncthreads();
    }
    if (tid == 0) perp += expf(-sd[0]);
    __syncthreads();
  }
  if (tid == 0) {
    out[NOUT]     = 1.25f * (*loss) / (float)NOUT;
    out[NOUT + 1] = perp;
  }
}

extern "C" void kernel_launch(void* const* d_in, const int* in_sizes, int n_in,
                              void* d_out, int out_size, void* d_ws, size_t ws_size,
                              hipStream_t stream) {
  const float* x   = (const float*)d_in[0];
  const float* cw  = (const float*)d_in[1];
  const float* gnw = (const float*)d_in[2];
  const float* gnb = (const float*)d_in[3];
  const float* emb = (const float*)d_in[4];
  float* out = (float*)d_out;
  char* ws = (char*)d_ws;
  float*     h      = (float*)(ws + OFF_H);
  double*    part   = (double*)(ws + OFF_PART);
  float*     musig  = (float*)(ws + OFF_MUSIG);
  float*     esq    = (float*)(ws + OFF_ESQ);
  unsigned*  counts = (unsigned*)(ws + OFF_CNT);
  float*     loss   = (float*)(ws + OFF_LOSS);
  _Float16*  embH   = (_Float16*)(ws + OFF_EMBH);
  _Float16*  wH     = (_Float16*)(ws + OFF_WH);
  _Float16*  wL     = (_Float16*)(ws + OFF_WL);

  hipLaunchKernelGGL(k_emb,   dim3(57),   dim3(256), 0, stream,
                     emb, cw, embH, wH, wL, esq, counts, loss);
  hipLaunchKernelGGL(k_conv2, dim3(512),  dim3(256), 0, stream, x, wH, wL, h, part);
  hipLaunchKernelGGL(k_stats, dim3(1),    dim3(32),  0, stream, part, musig);
  hipLaunchKernelGGL(k_vq2,   dim3(1024), dim3(256), 0, stream,
                     h, musig, gnw, gnb, embH, esq, emb, out, counts, loss);
  hipLaunchKernelGGL(k_final, dim3(1),    dim3(256), 0, stream, counts, loss, out);
}